// Round 1
// baseline (614.674 us; speedup 1.0000x reference)
//
#include <hip/hip_runtime.h>
#include <math.h>

// Problem constants: B=4, M=N=128, I=64, H=256, modes 16 (rows 0..15 and 112..127, cols 0..15)
#define TWO_PI 6.28318530717958647692f

// ---------------- FFT stage 1: column DFT (v -> k, 16 freqs) ----------------
// S1[b][i][u][k] = sum_v (x[b,u,v,i] - z[b,0,u,v,i]) * e^{-2pi i k v/128}
__global__ __launch_bounds__(256)
void k_fft1(const float* __restrict__ x, const float* __restrict__ z,
            float* __restrict__ S1) {
  const int t = threadIdx.x;
  const int bid = blockIdx.x;            // b*128 + u
  const int b = bid >> 7, u = bid & 127;
  __shared__ float diff[128 * 64];
  __shared__ float twc[128], tws[128];
  if (t < 128) {
    float s, c;
    sincosf(TWO_PI * (float)t / 128.0f, &s, &c);
    twc[t] = c; tws[t] = s;
  }
  const size_t bx = ((size_t)b * 16384 + (size_t)u * 128) * 64;
  const size_t bz = ((size_t)b * 2 * 16384 + (size_t)u * 128) * 64;
  #pragma unroll
  for (int j = 0; j < 32; ++j) {
    int idx = t + 256 * j;
    diff[idx] = x[bx + idx] - z[bz + idx];
  }
  __syncthreads();
  #pragma unroll
  for (int j = 0; j < 4; ++j) {
    int p = t + 256 * j;
    int i = p & 63, k = p >> 6;          // k in 0..15
    float ar = 0.f, ai = 0.f;
    #pragma unroll 8
    for (int v = 0; v < 128; ++v) {
      float d = diff[v * 64 + i];
      int w = (k * v) & 127;
      ar += d * twc[w];
      ai -= d * tws[w];
    }
    size_t o = ((size_t)(b * 64 + i) * 128 + u) * 16 + k;
    S1[2 * o] = ar; S1[2 * o + 1] = ai;
  }
}

// ---------------- FFT stage 2: row DFT (u -> m, 32 freqs) ----------------
// XF[b][mi][k][i], m = mi<16 ? mi : mi+96
__global__ __launch_bounds__(256)
void k_fft2(const float* __restrict__ S1, float* __restrict__ XF) {
  const int t = threadIdx.x;
  const int bid = blockIdx.x;            // b*64 + i
  const int b = bid >> 6, i = bid & 63;
  __shared__ float s1t[128 * 16 * 2];
  __shared__ float twc[128], tws[128];
  if (t < 128) {
    float s, c;
    sincosf(TWO_PI * (float)t / 128.0f, &s, &c);
    twc[t] = c; tws[t] = s;
  }
  const size_t base = (size_t)bid * 4096;
  #pragma unroll
  for (int j = 0; j < 16; ++j) s1t[t + 256 * j] = S1[base + t + 256 * j];
  __syncthreads();
  #pragma unroll
  for (int j = 0; j < 2; ++j) {
    int p = t + 256 * j;
    int mi = p >> 4, k = p & 15;
    int m = (mi < 16) ? mi : mi + 96;
    float ar = 0.f, ai = 0.f;
    #pragma unroll 8
    for (int u = 0; u < 128; ++u) {
      float sr = s1t[(u * 16 + k) * 2];
      float si = s1t[(u * 16 + k) * 2 + 1];
      int w = (m * u) & 127;
      float c = twc[w], s = tws[w];
      ar += sr * c + si * s;     // (sr+i si)(c - i s)
      ai += si * c - sr * s;
    }
    size_t o = (((size_t)(b * 32 + mi)) * 16 + k) * 64 + i;
    XF[2 * o] = ar; XF[2 * o + 1] = ai;
  }
}

// ---------------- complex einsum over input channels ----------------
// G[b][mi][k][o] = sum_i XF[b][mi][k][i] * w[i][o][xs][k]
__global__ __launch_bounds__(256)
void k_einsum(const float* __restrict__ XF, const float* __restrict__ fw1,
              const float* __restrict__ fw2, float* __restrict__ G) {
  const int t = threadIdx.x;
  const int bid = blockIdx.x;            // b*32 + mi
  const int mi = bid & 31;
  const int xs = (mi < 16) ? mi : mi - 16;
  const float* __restrict__ w = (mi < 16) ? fw1 : fw2;
  __shared__ float xin[16 * 64 * 2];
  const size_t base = (size_t)bid * 2048;
  #pragma unroll
  for (int j = 0; j < 8; ++j) xin[t + 256 * j] = XF[base + t + 256 * j];
  __syncthreads();
  #pragma unroll
  for (int j = 0; j < 4; ++j) {
    int p = t + 256 * j;
    int o = p & 63, k = p >> 6;
    float ar = 0.f, ai = 0.f;
    #pragma unroll 4
    for (int i = 0; i < 64; ++i) {
      float xr = xin[(k * 64 + i) * 2];
      float xi = xin[(k * 64 + i) * 2 + 1];
      int widx = (((i * 64 + o) * 16 + xs) * 16 + k) * 2;
      float wr = w[widx], wi = w[widx + 1];
      ar += xr * wr - xi * wi;
      ai += xr * wi + xi * wr;
    }
    size_t og = ((size_t)bid * 16 + k) * 64 + o;
    G[2 * og] = ar; G[2 * og + 1] = ai;
  }
}

// ---------------- inverse stage 1: k -> v with hermitian weights ----------------
// T[b][v][mi][o] = sum_k c_k G[b][mi][k][o] e^{+2pi i k v/128},  c_0=1, c_k=2
__global__ __launch_bounds__(256)
void k_inv1(const float* __restrict__ G, float* __restrict__ T) {
  const int t = threadIdx.x;
  const int bid = blockIdx.x;            // b*32 + mi
  const int b = bid >> 5, mi = bid & 31;
  __shared__ float gg[16 * 64 * 2];
  __shared__ float twc[128], tws[128];
  if (t < 128) {
    float s, c;
    sincosf(TWO_PI * (float)t / 128.0f, &s, &c);
    twc[t] = c; tws[t] = s;
  }
  const size_t base = (size_t)bid * 2048;
  #pragma unroll
  for (int j = 0; j < 8; ++j) gg[t + 256 * j] = G[base + t + 256 * j];
  __syncthreads();
  #pragma unroll
  for (int j = 0; j < 32; ++j) {
    int p = t + 256 * j;
    int o = p & 63, v = p >> 6;          // v in 0..127
    float tr = 0.f, ti = 0.f;
    #pragma unroll
    for (int k = 0; k < 16; ++k) {
      float gr = gg[(k * 64 + o) * 2];
      float gi = gg[(k * 64 + o) * 2 + 1];
      int w = (k * v) & 127;
      float c = twc[w], s = tws[w];
      float ck = (k == 0) ? 1.f : 2.f;
      tr += ck * (gr * c - gi * s);      // (gr+i gi)(c + i s)
      ti += ck * (gr * s + gi * c);
    }
    size_t ot = (((size_t)(b * 128 + v)) * 32 + mi) * 64 + o;
    T[2 * ot] = tr; T[2 * ot + 1] = ti;
  }
}

// ---------------- inverse stage 2: m -> u, take Re, scale ----------------
// xo[b][u][v][o] = (1/16384) sum_mi [Tr cos(2pi m u/128) - Ti sin(...)]
__global__ __launch_bounds__(256)
void k_inv2(const float* __restrict__ T, float* __restrict__ xo) {
  const int t = threadIdx.x;
  const int bid = blockIdx.x;            // b*128 + v
  const int b = bid >> 7, v = bid & 127;
  __shared__ float ts[32 * 64 * 2];
  __shared__ float twc[128], tws[128];
  if (t < 128) {
    float s, c;
    sincosf(TWO_PI * (float)t / 128.0f, &s, &c);
    twc[t] = c; tws[t] = s;
  }
  const size_t base = (size_t)bid * 4096;
  #pragma unroll
  for (int j = 0; j < 16; ++j) ts[t + 256 * j] = T[base + t + 256 * j];
  __syncthreads();
  #pragma unroll
  for (int j = 0; j < 32; ++j) {
    int p = t + 256 * j;
    int o = p & 63, u = p >> 6;          // u in 0..127
    float acc = 0.f;
    #pragma unroll
    for (int mi = 0; mi < 32; ++mi) {
      int m = (mi < 16) ? mi : mi + 96;
      int w = (m * u) & 127;
      float2 tv = *(const float2*)&ts[(mi * 64 + o) * 2];
      acc += tv.x * twc[w] - tv.y * tws[w];
    }
    xo[((size_t)b * 16384 + (size_t)u * 128 + v) * 64 + o] = acc * (1.0f / 16384.0f);
  }
}

// ---------------- GEMM1: h1 = xo(65536x64) @ W(64x256) + bias ----------------
__global__ __launch_bounds__(256)
void k_gemm1(const float* __restrict__ A, const float* __restrict__ W,
             const float* __restrict__ bias, float* __restrict__ H) {
  const int t = threadIdx.x;
  const int bid = blockIdx.x;
  const int rb = bid >> 2, cb = bid & 3;
  const int row0 = rb * 64, colb = cb * 64;
  __shared__ float at[64 * 64];   // [k][r]
  __shared__ float bt[64 * 64];   // [k][c]
  {
    const float4* A4 = (const float4*)(A + (size_t)row0 * 64);
    int r = t >> 2, k0 = (t & 3) * 16;
    #pragma unroll
    for (int m = 0; m < 4; ++m) {
      float4 vv = A4[t * 4 + m];
      at[(k0 + m * 4 + 0) * 64 + r] = vv.x;
      at[(k0 + m * 4 + 1) * 64 + r] = vv.y;
      at[(k0 + m * 4 + 2) * 64 + r] = vv.z;
      at[(k0 + m * 4 + 3) * 64 + r] = vv.w;
    }
    int kw = t >> 2, c0 = (t & 3) * 16;
    #pragma unroll
    for (int m = 0; m < 4; ++m) {
      float4 vv = *(const float4*)&W[(size_t)kw * 256 + colb + c0 + m * 4];
      *(float4*)&bt[kw * 64 + c0 + m * 4] = vv;
    }
  }
  __syncthreads();
  const int rr = (t >> 4) * 4, cc = (t & 15) * 4;
  float acc[4][4] = {};
  #pragma unroll 16
  for (int k = 0; k < 64; ++k) {
    const float4 a = *(const float4*)&at[k * 64 + rr];
    const float4 bb = *(const float4*)&bt[k * 64 + cc];
    float av[4] = {a.x, a.y, a.z, a.w};
    float bv[4] = {bb.x, bb.y, bb.z, bb.w};
    #pragma unroll
    for (int i = 0; i < 4; ++i)
      #pragma unroll
      for (int jq = 0; jq < 4; ++jq)
        acc[i][jq] += av[i] * bv[jq];
  }
  #pragma unroll
  for (int i = 0; i < 4; ++i)
    #pragma unroll
    for (int jq = 0; jq < 4; ++jq) {
      int col = colb + cc + jq;
      H[(size_t)(row0 + rr + i) * 256 + col] = acc[i][jq] + bias[col];
    }
}

// ---------------- stats over 65536xC matrix, group = 16 channels ----------------
__global__ __launch_bounds__(256)
void k_stats256(const float* __restrict__ src, float* __restrict__ stats) {
  const int t = threadIdx.x;
  const int rowbase = blockIdx.x * 64;
  const int b = rowbase >> 14;
  float sum = 0.f, ssq = 0.f;
  for (int r = 0; r < 64; ++r) {
    float v = src[(size_t)(rowbase + r) * 256 + t];
    sum += v; ssq += v * v;
  }
  #pragma unroll
  for (int off = 1; off < 16; off <<= 1) {
    sum += __shfl_xor(sum, off);
    ssq += __shfl_xor(ssq, off);
  }
  if ((t & 15) == 0) {
    int g = t >> 4;
    atomicAdd(&stats[(b * 16 + g) * 2], sum);
    atomicAdd(&stats[(b * 16 + g) * 2 + 1], ssq);
  }
}

__global__ __launch_bounds__(256)
void k_stats64(const float* __restrict__ src, float* __restrict__ stats) {
  const int t = threadIdx.x;
  const int rowbase = blockIdx.x * 256;
  const int b = rowbase >> 14;
  const int col = t & 63, rb = t >> 6;
  float sum = 0.f, ssq = 0.f;
  for (int j = 0; j < 64; ++j) {
    int r = rb + 4 * j;
    float v = src[(size_t)(rowbase + r) * 64 + col];
    sum += v; ssq += v * v;
  }
  #pragma unroll
  for (int off = 1; off < 16; off <<= 1) {
    sum += __shfl_xor(sum, off);
    ssq += __shfl_xor(ssq, off);
  }
  if ((t & 15) == 0) {
    int g = col >> 4;
    atomicAdd(&stats[(b * 4 + g) * 2], sum);
    atomicAdd(&stats[(b * 4 + g) * 2 + 1], ssq);
  }
}

// ---------------- GEMM2: h2 = relu(norm1(h1)) @ W2(256x64) + b2 ----------------
__global__ __launch_bounds__(256)
void k_gemm2(const float* __restrict__ H1, const float* __restrict__ stats,
             const float* __restrict__ gw, const float* __restrict__ gb,
             const float* __restrict__ W2, const float* __restrict__ b2,
             float* __restrict__ H2) {
  const int t = threadIdx.x;
  const int row0 = blockIdx.x * 64;
  const int b = row0 >> 14;
  __shared__ float at[64 * 64];
  __shared__ float bt[64 * 64];
  const float inv_cnt = 1.0f / 262144.0f;
  const int rr = (t >> 4) * 4, cc = (t & 15) * 4;
  float acc[4][4] = {};
  for (int ks = 0; ks < 256; ks += 64) {
    __syncthreads();
    {
      int r = t >> 2, k0 = (t & 3) * 16;
      #pragma unroll
      for (int m = 0; m < 4; ++m) {
        float4 vv = *(const float4*)&H1[(size_t)(row0 + r) * 256 + ks + k0 + m * 4];
        float vals[4] = {vv.x, vv.y, vv.z, vv.w};
        #pragma unroll
        for (int q = 0; q < 4; ++q) {
          int col = ks + k0 + m * 4 + q;
          int g = col >> 4;
          float sm = stats[(b * 16 + g) * 2];
          float ssq = stats[(b * 16 + g) * 2 + 1];
          float mean = sm * inv_cnt;
          float var = ssq * inv_cnt - mean * mean;
          float rstd = rsqrtf(var + 1e-5f);
          float val = (vals[q] - mean) * rstd * gw[col] + gb[col];
          at[(k0 + m * 4 + q) * 64 + r] = fmaxf(val, 0.f);
        }
      }
      int kw = t >> 2, c0 = (t & 3) * 16;
      #pragma unroll
      for (int m = 0; m < 4; ++m) {
        float4 vv = *(const float4*)&W2[(size_t)(ks + kw) * 64 + c0 + m * 4];
        *(float4*)&bt[kw * 64 + c0 + m * 4] = vv;
      }
    }
    __syncthreads();
    #pragma unroll 16
    for (int k = 0; k < 64; ++k) {
      const float4 a = *(const float4*)&at[k * 64 + rr];
      const float4 bb = *(const float4*)&bt[k * 64 + cc];
      float av[4] = {a.x, a.y, a.z, a.w};
      float bv[4] = {bb.x, bb.y, bb.z, bb.w};
      #pragma unroll
      for (int i = 0; i < 4; ++i)
        #pragma unroll
        for (int jq = 0; jq < 4; ++jq)
          acc[i][jq] += av[i] * bv[jq];
    }
  }
  #pragma unroll
  for (int i = 0; i < 4; ++i)
    #pragma unroll
    for (int jq = 0; jq < 4; ++jq)
      H2[(size_t)(row0 + rr + i) * 64 + cc + jq] = acc[i][jq] + b2[cc + jq];
}

// ---------------- h3 = res + norm2(h2); write out; accumulate stats3 ----------------
__global__ __launch_bounds__(256)
void k_h3(const float* __restrict__ H2, const float* __restrict__ stats2,
          const float* __restrict__ g2w, const float* __restrict__ g2b,
          const float* __restrict__ z, int br,
          float* __restrict__ out, float* __restrict__ stats3) {
  const int t = threadIdx.x;
  const int rowbase = blockIdx.x * 256;
  const int b = rowbase >> 14;
  const int col = t & 63, rb = t >> 6;
  const int g = col >> 4;
  const float inv_cnt = 1.0f / 262144.0f;
  float sm = stats2[(b * 4 + g) * 2];
  float sq = stats2[(b * 4 + g) * 2 + 1];
  float mean = sm * inv_cnt;
  float var = sq * inv_cnt - mean * mean;
  float rstd = rsqrtf(var + 1e-5f);
  float wv = g2w[col], bv = g2b[col];
  float sum = 0.f, ssq = 0.f;
  for (int j = 0; j < 64; ++j) {
    int r = rowbase + rb + 4 * j;
    int local = r & 16383;
    size_t idx = (size_t)r * 64 + col;
    size_t zidx = ((size_t)(b * 2 + br) * 16384 + local) * 64 + col;
    float val = z[zidx] + (H2[idx] - mean) * rstd * wv + bv;
    out[zidx] = val;
    sum += val; ssq += val * val;
  }
  #pragma unroll
  for (int off = 1; off < 16; off <<= 1) {
    sum += __shfl_xor(sum, off);
    ssq += __shfl_xor(ssq, off);
  }
  if ((t & 15) == 0) {
    atomicAdd(&stats3[(b * 4 + g) * 2], sum);
    atomicAdd(&stats3[(b * 4 + g) * 2 + 1], ssq);
  }
}

// ---------------- final in-place norm3 on the branch slot ----------------
__global__ __launch_bounds__(256)
void k_final(float* __restrict__ out, const float* __restrict__ stats3,
             const float* __restrict__ g3w, const float* __restrict__ g3b, int br) {
  const float inv_cnt = 1.0f / 262144.0f;
  const size_t n = (size_t)4 * 16384 * 64;       // 4 * 2^20
  for (size_t idx = (size_t)blockIdx.x * 256 + threadIdx.x; idx < n;
       idx += (size_t)gridDim.x * 256) {
    int col = (int)(idx & 63);
    int b = (int)(idx >> 20);
    int g = col >> 4;
    float sm = stats3[(b * 4 + g) * 2];
    float sq = stats3[(b * 4 + g) * 2 + 1];
    float mean = sm * inv_cnt;
    float rstd = rsqrtf(sq * inv_cnt - mean * mean + 1e-5f);
    size_t local = idx & ((((size_t)1) << 20) - 1);
    size_t oidx = (((size_t)(b * 2 + br)) << 20) + local;
    out[oidx] = (out[oidx] - mean) * rstd * g3w[col] + g3b[col];
  }
}

extern "C" void kernel_launch(void* const* d_in, const int* in_sizes, int n_in,
                              void* d_out, int out_size, void* d_ws, size_t ws_size,
                              hipStream_t stream) {
  const float* z   = (const float*)d_in[0];
  const float* x   = (const float*)d_in[1];
  const float* fw1 = (const float*)d_in[2];
  const float* fw2 = (const float*)d_in[3];
  const float* P[20];
  for (int i = 0; i < 20; ++i) P[i] = (const float*)d_in[4 + i];
  // P[0..9]  = b_{l1w,l1b,l2w,l2b,g1w,g1b,g2w,g2b,g3w,g3b}
  // P[10..19]= f_{...}

  float* ws = (float*)d_ws;
  float* xo = ws;                     // 4,194,304
  float* S1 = ws + 4194304;           // 1,048,576
  float* XF = ws + 5242880;           //   262,144
  float* G  = ws + 5505024;           //   262,144
  float* T  = ws + 5767168;           // 2,097,152
  float* h1 = ws + 7864320;           // 16,777,216
  float* h2 = ws + 24641536;          // 4,194,304
  float* st = ws + 28835840;          // 192 floats: s1@0(128), s2@128(32), s3@160(32)
  float* out = (float*)d_out;

  k_fft1<<<512, 256, 0, stream>>>(x, z, S1);
  k_fft2<<<256, 256, 0, stream>>>(S1, XF);
  k_einsum<<<128, 256, 0, stream>>>(XF, fw1, fw2, G);
  k_inv1<<<128, 256, 0, stream>>>(G, T);
  k_inv2<<<512, 256, 0, stream>>>(T, xo);

  for (int br = 0; br < 2; ++br) {
    const float* const* q = P + br * 10;
    hipMemsetAsync(st, 0, 192 * sizeof(float), stream);
    k_gemm1<<<4096, 256, 0, stream>>>(xo, q[0], q[1], h1);
    k_stats256<<<1024, 256, 0, stream>>>(h1, st);
    k_gemm2<<<1024, 256, 0, stream>>>(h1, st, q[4], q[5], q[2], q[3], h2);
    k_stats64<<<256, 256, 0, stream>>>(h2, st + 128);
    k_h3<<<256, 256, 0, stream>>>(h2, st + 128, q[6], q[7], z, br, out, st + 160);
    k_final<<<2048, 256, 0, stream>>>(out, st + 160, q[8], q[9], br);
  }
}

// Round 2
// 457.510 us; speedup vs baseline: 1.3435x; 1.3435x over previous
//
#include <hip/hip_runtime.h>
#include <math.h>

#define TWO_PI 6.28318530717958647692f

// ws float offsets
#define OFF_XO    0u
#define OFF_S1    4194304u
#define OFF_XF    5242880u
#define OFF_G     5505024u
#define OFF_T     5767168u
#define OFF_WT    7864320u
#define OFF_TW1   12058624u
#define OFF_TW2   12062720u
#define OFF_CK    12079104u
#define OFF_CM    12087296u
#define OFF_H2    12095488u
#define OFF_SS    20484096u
#define OFF_CS    20500480u
#define OFF_COLQ  20500736u
#define OFF_COLH2 20502784u
#define OFF_ZST   20504320u
#define OFF_COLA  20505344u
#define OFF_GN1   20507392u
#define OFF_ALPHA 20507648u
#define OFF_BETA  20508160u
#define OFF_GN3   20508672u
#define ZERO_CNT  21248u   // SS..ZST contiguous

// ---------------- twiddle LUT fill ----------------
__global__ __launch_bounds__(256)
void k_twfill(float* __restrict__ lut) {
  int idx = blockIdx.x * 256 + threadIdx.x;
  const float step = TWO_PI / 128.0f;
  if (idx < 4096) {                       // TW1t[v][2k+p]
    int v = idx >> 5, j = idx & 31, k = j >> 1, p = j & 1;
    float s, c; sincosf(step * (float)((k * v) & 127), &s, &c);
    lut[idx] = p ? -s : c;
  } else if (idx < 20480) {               // TW2t[2u+pp][2mi+p]
    int li = idx - 4096; int q = li >> 6, j3 = li & 63;
    int u = q >> 1, pp = q & 1, mi = j3 >> 1, p = j3 & 1;
    int m = mi < 16 ? mi : mi + 96;
    float s, c; sincosf(step * (float)((m * u) & 127), &s, &c);
    lut[idx] = pp == 0 ? (p == 0 ? c : -s) : (p == 0 ? s : c);
  } else if (idx < 28672) {               // CKt[2k+pp][2v+p]
    int li = idx - 20480; int j4 = li >> 8, r5 = li & 255;
    int k = j4 >> 1, pp = j4 & 1, v = r5 >> 1, p = r5 & 1;
    float ck = k ? 2.f : 1.f;
    float s, c; sincosf(step * (float)((k * v) & 127), &s, &c);
    lut[idx] = pp == 0 ? (p == 0 ? ck * c : ck * s) : (p == 0 ? -ck * s : ck * c);
  } else if (idx < 36864) {               // CMt[2mi+p][u]  (scale folded)
    int li = idx - 28672; int j5 = li >> 7, u = li & 127;
    int mi = j5 >> 1, p = j5 & 1; int m = mi < 16 ? mi : mi + 96;
    float s, c; sincosf(step * (float)((m * u) & 127), &s, &c);
    lut[idx] = (p == 0 ? c : -s) * (1.0f / 16384.0f);
  }
}

// ---------------- weight transpose: wt[mi][k][i][o][2] ----------------
__global__ __launch_bounds__(256)
void k_wtrans(const float* __restrict__ fw1, const float* __restrict__ fw2,
              float* __restrict__ wt) {
  int bid = blockIdx.x, t = threadIdx.x;
  int mi = bid >> 4, ic = bid & 15;
  int i = ic * 4 + (t >> 6), o = t & 63;
  int xs = mi & 15;
  const float* src = (mi < 16 ? fw1 : fw2) + (size_t)(((i * 64 + o) * 16 + xs) * 16) * 2;
  float4 r[8];
  #pragma unroll
  for (int j = 0; j < 8; ++j) r[j] = ((const float4*)src)[j];
  float2* dst = (float2*)wt;
  #pragma unroll
  for (int j = 0; j < 8; ++j) {
    int k0 = 2 * j;
    dst[((size_t)(mi * 16 + k0) * 64 + i) * 64 + o]     = make_float2(r[j].x, r[j].y);
    dst[((size_t)(mi * 16 + k0 + 1) * 64 + i) * 64 + o] = make_float2(r[j].z, r[j].w);
  }
}

// ---------------- fft1: per (b,u): S1[2u+p][k*64+i] = TW1t x diff ----------------
__global__ __launch_bounds__(256)
void k_fft1(const float* __restrict__ x, const float* __restrict__ z,
            const float* __restrict__ TW1t, float* __restrict__ S1) {
  __shared__ float diff[128 * 64];
  int t = threadIdx.x, bid = blockIdx.x;
  int b = bid >> 7, u = bid & 127;
  size_t bx = ((size_t)b * 16384 + (size_t)u * 128) * 64;
  size_t bz = ((size_t)b * 32768 + (size_t)u * 128) * 64;
  #pragma unroll
  for (int j = 0; j < 32; ++j) { int idx = t + 256 * j; diff[idx] = x[bx + idx] - z[bz + idx]; }
  __syncthreads();
  int kk = t >> 4, i0 = (t & 15) * 4;
  float r0[4] = {}, r1[4] = {};
  #pragma unroll 4
  for (int v = 0; v < 128; ++v) {
    float2 tw = *(const float2*)&TW1t[v * 32 + kk * 2];
    float4 d = *(const float4*)&diff[v * 64 + i0];
    float dv[4] = {d.x, d.y, d.z, d.w};
    #pragma unroll
    for (int q = 0; q < 4; ++q) { r0[q] += tw.x * dv[q]; r1[q] += tw.y * dv[q]; }
  }
  size_t o0 = ((size_t)b * 256 + 2 * u) * 1024 + kk * 64 + i0;
  *(float4*)&S1[o0]        = make_float4(r0[0], r0[1], r0[2], r0[3]);
  *(float4*)&S1[o0 + 1024] = make_float4(r1[0], r1[1], r1[2], r1[3]);
}

// ---------------- fft2: per (b,colchunk32): XF[j3][col] = TW2t^T x S1 ----------------
__global__ __launch_bounds__(256)
void k_fft2(const float* __restrict__ S1, const float* __restrict__ TW2t,
            float* __restrict__ XF) {
  __shared__ float Bs[256 * 32];
  int t = threadIdx.x, bid = blockIdx.x;
  int b = bid >> 5, ch = bid & 31;
  size_t sbase = (size_t)b * 262144 + ch * 32;
  #pragma unroll
  for (int j = 0; j < 32; ++j) {
    int idx = t + 256 * j; int q = idx >> 5, c = idx & 31;
    Bs[idx] = S1[sbase + (size_t)q * 1024 + c];
  }
  __syncthreads();
  int r0 = (t >> 4) * 4, c0 = (t & 15) * 2;
  float acc[4][2] = {};
  #pragma unroll 4
  for (int q = 0; q < 256; ++q) {
    float4 a = *(const float4*)&TW2t[q * 64 + r0];
    float2 bb = *(const float2*)&Bs[q * 32 + c0];
    float av[4] = {a.x, a.y, a.z, a.w};
    #pragma unroll
    for (int i = 0; i < 4; ++i) { acc[i][0] += av[i] * bb.x; acc[i][1] += av[i] * bb.y; }
  }
  #pragma unroll
  for (int i = 0; i < 4; ++i)
    *(float2*)&XF[(size_t)b * 65536 + (size_t)(r0 + i) * 1024 + ch * 32 + c0] =
        make_float2(acc[i][0], acc[i][1]);
}

// ---------------- einsum: per (mi,k): G[2k+p][o] = sum_i XF * wt ----------------
__global__ __launch_bounds__(256)
void k_einsum(const float* __restrict__ XF, const float* __restrict__ wt,
              float* __restrict__ G) {
  __shared__ float xin[4][2][64];
  int t = threadIdx.x, bid = blockIdx.x;
  int mi = bid >> 4, k = bid & 15;
  #pragma unroll
  for (int rep = 0; rep < 2; ++rep) {
    int f = rep * 256 + t; int bb = f >> 7, rem = f & 127, p = rem >> 6, i = rem & 63;
    xin[bb][p][i] = XF[(size_t)bb * 65536 + (size_t)(2 * mi + p) * 1024 + k * 64 + i];
  }
  __syncthreads();
  int b = t >> 6, o = t & 63;
  float gr = 0.f, gi = 0.f;
  const float2* w2 = (const float2*)wt + (size_t)(mi * 16 + k) * 4096 + o;
  #pragma unroll 8
  for (int i = 0; i < 64; ++i) {
    float2 w = w2[(size_t)i * 64];
    float xr = xin[b][0][i], xi = xin[b][1][i];
    gr += xr * w.x - xi * w.y;
    gi += xr * w.y + xi * w.x;
  }
  size_t gb = ((size_t)(b * 32 + mi) * 32 + 2 * k) * 64 + o;
  G[gb] = gr; G[gb + 64] = gi;
}

// ---------------- inv1: per (b,mi,vq): T rows = CKt^T x GG ----------------
__global__ __launch_bounds__(256)
void k_inv1(const float* __restrict__ G, const float* __restrict__ CKt,
            float* __restrict__ T) {
  __shared__ float GG[32 * 64];
  int t = threadIdx.x, bid = blockIdx.x;
  int b = bid >> 7, mi = (bid >> 2) & 31, vq = bid & 3;
  size_t gbase = (size_t)(b * 32 + mi) * 2048;
  #pragma unroll
  for (int j = 0; j < 8; ++j) GG[t + 256 * j] = G[gbase + t + 256 * j];
  __syncthreads();
  int r0 = (t >> 4) * 4, o0 = (t & 15) * 4;
  float acc[4][4] = {};
  #pragma unroll 4
  for (int j4 = 0; j4 < 32; ++j4) {
    float4 a = *(const float4*)&CKt[j4 * 256 + vq * 64 + r0];
    float4 bb = *(const float4*)&GG[j4 * 64 + o0];
    float av[4] = {a.x, a.y, a.z, a.w}, bv[4] = {bb.x, bb.y, bb.z, bb.w};
    #pragma unroll
    for (int i = 0; i < 4; ++i)
      #pragma unroll
      for (int j = 0; j < 4; ++j) acc[i][j] += av[i] * bv[j];
  }
  #pragma unroll
  for (int ii = 0; ii < 4; ++ii) {
    int r = vq * 64 + r0 + ii; int v = r >> 1, p = r & 1;
    *(float4*)&T[((size_t)(b * 128 + v) * 64 + 2 * mi + p) * 64 + o0] =
        make_float4(acc[ii][0], acc[ii][1], acc[ii][2], acc[ii][3]);
  }
}

// ---------------- inv2: per (b,v,uh): xo[u][o] = CMt^T x Ts ----------------
__global__ __launch_bounds__(256)
void k_inv2(const float* __restrict__ T, const float* __restrict__ CMt,
            float* __restrict__ xo) {
  __shared__ float Ts[64 * 64];
  int t = threadIdx.x, bid = blockIdx.x;
  int b = bid >> 8, v = (bid >> 1) & 127, uh = bid & 1;
  size_t tb = (size_t)(b * 128 + v) * 4096;
  #pragma unroll
  for (int j = 0; j < 16; ++j) Ts[t + 256 * j] = T[tb + t + 256 * j];
  __syncthreads();
  int u0 = uh * 64 + (t >> 4) * 4, o0 = (t & 15) * 4;
  float acc[4][4] = {};
  #pragma unroll 4
  for (int j5 = 0; j5 < 64; ++j5) {
    float4 a = *(const float4*)&CMt[j5 * 128 + u0];
    float4 bb = *(const float4*)&Ts[j5 * 64 + o0];
    float av[4] = {a.x, a.y, a.z, a.w}, bv[4] = {bb.x, bb.y, bb.z, bb.w};
    #pragma unroll
    for (int i = 0; i < 4; ++i)
      #pragma unroll
      for (int j = 0; j < 4; ++j) acc[i][j] += av[i] * bv[j];
  }
  #pragma unroll
  for (int ii = 0; ii < 4; ++ii)
    *(float4*)&xo[(size_t)b * 1048576 + (size_t)(u0 + ii) * 8192 + v * 64 + o0] =
        make_float4(acc[ii][0], acc[ii][1], acc[ii][2], acc[ii][3]);
}

// ---------------- xo stats: SS[b]=X^T X, CS[b]=col sums ----------------
__global__ __launch_bounds__(256)
void k_xostats(const float* __restrict__ xo, float* __restrict__ SS,
               float* __restrict__ CS) {
  __shared__ float Xs[128 * 64];
  int t = threadIdx.x, bid = blockIdx.x;
  int b = bid >> 7, rc = bid & 127;
  size_t base = (size_t)b * 1048576 + (size_t)rc * 8192;
  #pragma unroll
  for (int j = 0; j < 32; ++j) Xs[t + 256 * j] = xo[base + t + 256 * j];
  __syncthreads();
  int c1 = (t >> 4) * 4, c2 = (t & 15) * 4;
  float acc[4][4] = {};
  #pragma unroll 2
  for (int r = 0; r < 128; ++r) {
    float4 a = *(const float4*)&Xs[r * 64 + c1];
    float4 bb = *(const float4*)&Xs[r * 64 + c2];
    float av[4] = {a.x, a.y, a.z, a.w}, bv[4] = {bb.x, bb.y, bb.z, bb.w};
    #pragma unroll
    for (int i = 0; i < 4; ++i)
      #pragma unroll
      for (int j = 0; j < 4; ++j) acc[i][j] += av[i] * bv[j];
  }
  float* ssb = SS + b * 4096;
  #pragma unroll
  for (int i = 0; i < 4; ++i)
    #pragma unroll
    for (int j = 0; j < 4; ++j) atomicAdd(&ssb[(c1 + i) * 64 + c2 + j], acc[i][j]);
  if (t < 64) {
    float s = 0.f;
    for (int r = 0; r < 128; ++r) s += Xs[r * 64 + t];
    atomicAdd(&CS[b * 64 + t], s);
  }
}

// ---------------- per-col quadratic form Q_c = w^T SS w, A_c = CS.w ----------------
__global__ __launch_bounds__(256)
void k_colq(const float* __restrict__ bW1, const float* __restrict__ fW1,
            const float* __restrict__ SS, const float* __restrict__ CS,
            float* __restrict__ colq, float* __restrict__ cola) {
  int bid = blockIdx.x, t = threadIdx.x;
  int br = bid >> 5, b = (bid >> 3) & 3, jc = bid & 7;
  const float* W1 = br ? fW1 : bW1;
  float w[64];
  #pragma unroll
  for (int l = 0; l < 64; ++l) w[l] = W1[l * 256 + t];
  const float* ssb = SS + b * 4096;
  float q = 0.f;
  for (int jj = 0; jj < 8; ++jj) {
    int j = jc * 8 + jj;
    float sj = 0.f;
    #pragma unroll
    for (int l = 0; l < 64; ++l) sj += ssb[j * 64 + l] * w[l];
    q += W1[j * 256 + t] * sj;
  }
  atomicAdd(&colq[(br * 4 + b) * 256 + t], q);
  if (jc == 0) {
    float a = 0.f;
    #pragma unroll
    for (int l = 0; l < 64; ++l) a += CS[b * 64 + l] * w[l];
    cola[(br * 4 + b) * 256 + t] = a;
  }
}

// ---------------- gn1 group stats (analytic) ----------------
__global__ __launch_bounds__(256)
void k_gstats(const float* __restrict__ colq, const float* __restrict__ cola,
              const float* __restrict__ bb1, const float* __restrict__ fb1,
              float* __restrict__ gn1) {
  int t = threadIdx.x; if (t >= 128) return;
  int br = t >> 6, bg = t & 63, b = bg >> 4, g = bg & 15;
  const float* b1 = br ? fb1 : bb1;
  const float invR = 1.0f / 16384.0f;
  float se = 0.f, sq = 0.f;
  for (int ci = 0; ci < 16; ++ci) {
    int c = g * 16 + ci;
    float A = cola[(br * 4 + b) * 256 + c];
    float Q = colq[(br * 4 + b) * 256 + c];
    float bc = b1[c];
    se += A * invR + bc;
    sq += (Q + 2.f * bc * A) * invR + bc * bc;
  }
  float mean = se * 0.0625f;
  float var = sq * 0.0625f - mean * mean;
  gn1[((br * 4 + b) * 16 + g) * 2] = mean;
  gn1[((br * 4 + b) * 16 + g) * 2 + 1] = rsqrtf(var + 1e-5f);
}

// ---------------- z stats per (b,br,col) ----------------
__global__ __launch_bounds__(256)
void k_zstats(const float* __restrict__ z, float* __restrict__ zst) {
  __shared__ float red[4][64][2];
  int t = threadIdx.x, bid = blockIdx.x;
  int b2 = bid >> 6, rc = bid & 63;
  int col = t & 63, rq = t >> 6;
  size_t base = (size_t)b2 * 1048576 + (size_t)rc * 16384;
  float s = 0.f, q = 0.f;
  for (int j = 0; j < 64; ++j) {
    float v = z[base + (size_t)(rq + 4 * j) * 64 + col];
    s += v; q += v * v;
  }
  red[rq][col][0] = s; red[rq][col][1] = q;
  __syncthreads();
  if (t < 64) {
    float ss = 0.f, qq = 0.f;
    #pragma unroll
    for (int r = 0; r < 4; ++r) { ss += red[r][t][0]; qq += red[r][t][1]; }
    atomicAdd(&zst[(b2 * 64 + t) * 2], ss);
    atomicAdd(&zst[(b2 * 64 + t) * 2 + 1], qq);
  }
}

// ---------------- fused FFN: gemm1+gn1+relu+gemm2 (+h2 col sums) ----------------
__global__ __launch_bounds__(256)
void k_ffn(const float* __restrict__ xo, const float* __restrict__ W1,
           const float* __restrict__ b1, const float* __restrict__ g1w,
           const float* __restrict__ g1b, const float* __restrict__ gn1b,
           const float* __restrict__ W2, const float* __restrict__ b2,
           const float* __restrict__ z, int br,
           float* __restrict__ h2, float* __restrict__ colh2) {
  __shared__ float at[64 * 64];
  __shared__ float wbuf[64 * 64];
  __shared__ float a2[64 * 65];
  int t = threadIdx.x;
  int rows0 = blockIdx.x * 64;
  int b = rows0 >> 14;
  {
    int r = t >> 2, k0 = (t & 3) * 16;
    const float* src = xo + (size_t)(rows0 + r) * 64 + k0;
    #pragma unroll
    for (int m = 0; m < 4; ++m) {
      float4 vv = *(const float4*)&src[m * 4];
      at[(k0 + m * 4 + 0) * 64 + r] = vv.x;
      at[(k0 + m * 4 + 1) * 64 + r] = vv.y;
      at[(k0 + m * 4 + 2) * 64 + r] = vv.z;
      at[(k0 + m * 4 + 3) * 64 + r] = vv.w;
    }
  }
  int rr = (t >> 4) * 4, cc = (t & 15) * 4;
  float h2acc[4][4] = {};
  for (int cs = 0; cs < 4; ++cs) {
    __syncthreads();                       // prev gemm2 done / at staged
    {
      int kw = t >> 2, c0 = (t & 3) * 16;
      #pragma unroll
      for (int m = 0; m < 4; ++m)
        *(float4*)&wbuf[kw * 64 + c0 + m * 4] =
            *(const float4*)&W1[(size_t)kw * 256 + cs * 64 + c0 + m * 4];
    }
    __syncthreads();
    float s[4][4] = {};
    #pragma unroll 8
    for (int k = 0; k < 64; ++k) {
      float4 a = *(const float4*)&at[k * 64 + rr];
      float4 bb = *(const float4*)&wbuf[k * 64 + cc];
      float av[4] = {a.x, a.y, a.z, a.w}, bv[4] = {bb.x, bb.y, bb.z, bb.w};
      #pragma unroll
      for (int i = 0; i < 4; ++i)
        #pragma unroll
        for (int j = 0; j < 4; ++j) s[i][j] += av[i] * bv[j];
    }
    __syncthreads();                       // all done reading wbuf
    {
      int colb = cs * 64 + cc;
      int g = colb >> 4;
      float gm = gn1b[(b * 16 + g) * 2], grs = gn1b[(b * 16 + g) * 2 + 1];
      float4 w4 = *(const float4*)&g1w[colb];
      float4 bn4 = *(const float4*)&g1b[colb];
      float4 l14 = *(const float4*)&b1[colb];
      float wv[4] = {w4.x, w4.y, w4.z, w4.w};
      float bv[4] = {bn4.x, bn4.y, bn4.z, bn4.w};
      float lv[4] = {l14.x, l14.y, l14.z, l14.w};
      #pragma unroll
      for (int i = 0; i < 4; ++i)
        #pragma unroll
        for (int q = 0; q < 4; ++q) {
          float val = ((s[i][q] + lv[q]) - gm) * grs * wv[q] + bv[q];
          a2[(cc + q) * 65 + rr + i] = fmaxf(val, 0.f);
        }
      // stage W2 chunk into wbuf
      int kw = t >> 2, c0 = (t & 3) * 16;
      #pragma unroll
      for (int m = 0; m < 4; ++m)
        *(float4*)&wbuf[kw * 64 + c0 + m * 4] =
            *(const float4*)&W2[(size_t)(cs * 64 + kw) * 64 + c0 + m * 4];
    }
    __syncthreads();
    #pragma unroll 8
    for (int cl = 0; cl < 64; ++cl) {
      float4 a = *(const float4*)&a2[cl * 65 + rr];
      float4 bb = *(const float4*)&wbuf[cl * 64 + cc];
      float av[4] = {a.x, a.y, a.z, a.w}, bv[4] = {bb.x, bb.y, bb.z, bb.w};
      #pragma unroll
      for (int i = 0; i < 4; ++i)
        #pragma unroll
        for (int j = 0; j < 4; ++j) h2acc[i][j] += av[i] * bv[j];
    }
  }
  // epilogue: bias, write h2, accumulate col sums (h2, h2^2, z*h2)
  float4 b24 = *(const float4*)&b2[cc];
  float bb2[4] = {b24.x, b24.y, b24.z, b24.w};
  float sum[4] = {}, ssq[4] = {}, szh[4] = {};
  size_t zrow0 = ((size_t)(b * 2 + br) * 16384 + (rows0 & 16383));
  #pragma unroll
  for (int i = 0; i < 4; ++i) {
    float4 zv = *(const float4*)&z[(zrow0 + rr + i) * 64 + cc];
    float zq[4] = {zv.x, zv.y, zv.z, zv.w};
    float vals[4];
    #pragma unroll
    for (int q = 0; q < 4; ++q) {
      float v = h2acc[i][q] + bb2[q];
      vals[q] = v;
      sum[q] += v; ssq[q] += v * v; szh[q] += zq[q] * v;
    }
    *(float4*)&h2[(size_t)(rows0 + rr + i) * 64 + cc] =
        make_float4(vals[0], vals[1], vals[2], vals[3]);
  }
  __syncthreads();
  float* scr = at;                          // reuse as [16][64][3]
  #pragma unroll
  for (int q = 0; q < 4; ++q) {
    int o = ((t >> 4) * 64 + cc + q) * 3;
    scr[o] = sum[q]; scr[o + 1] = ssq[q]; scr[o + 2] = szh[q];
  }
  __syncthreads();
  if (t < 64) {
    float s = 0.f, s2 = 0.f, s3 = 0.f;
    #pragma unroll
    for (int rg = 0; rg < 16; ++rg) {
      int o = (rg * 64 + t) * 3;
      s += scr[o]; s2 += scr[o + 1]; s3 += scr[o + 2];
    }
    float* ch = colh2 + ((size_t)(br * 4 + b) * 64 + t) * 3;
    atomicAdd(ch, s); atomicAdd(ch + 1, s2); atomicAdd(ch + 2, s3);
  }
}

// ---------------- final stats: gn2 (exact) + gn3 (analytic) ----------------
__global__ __launch_bounds__(256)
void k_fstats(const float* __restrict__ colh2, const float* __restrict__ zst,
              const float* __restrict__ bg2w, const float* __restrict__ bg2b,
              const float* __restrict__ fg2w, const float* __restrict__ fg2b,
              float* __restrict__ alpha, float* __restrict__ beta,
              float* __restrict__ gn3) {
  __shared__ float m2r2[32][2];
  __shared__ float ab[2][4][64][2];
  int t = threadIdx.x;
  const float invR = 1.0f / 16384.0f;
  if (t < 32) {
    int br = t >> 4, b = (t >> 2) & 3, g = t & 3;
    float se = 0.f, sq = 0.f;
    for (int ci = 0; ci < 16; ++ci) {
      const float* ch = colh2 + ((size_t)(br * 4 + b) * 64 + g * 16 + ci) * 3;
      se += ch[0]; sq += ch[1];
    }
    float mean = se * invR * 0.0625f;
    float Eq = sq * invR * 0.0625f;
    m2r2[t][0] = mean;
    m2r2[t][1] = rsqrtf(Eq - mean * mean + 1e-5f);
  }
  __syncthreads();
  #pragma unroll
  for (int rep = 0; rep < 2; ++rep) {
    int idx = t + rep * 256;
    int br = idx >> 8, b = (idx >> 6) & 3, c = idx & 63, g = c >> 4;
    const float* g2w = br ? fg2w : bg2w;
    const float* g2b = br ? fg2b : bg2b;
    float m2 = m2r2[(br * 4 + b) * 4 + g][0];
    float r2 = m2r2[(br * 4 + b) * 4 + g][1];
    float a = r2 * g2w[c];
    float bt = g2b[c] - m2 * a;
    ab[br][b][c][0] = a; ab[br][b][c][1] = bt;
    alpha[(br * 4 + b) * 64 + c] = a;
    beta[(br * 4 + b) * 64 + c] = bt;
  }
  __syncthreads();
  if (t < 32) {
    int br = t >> 4, b = (t >> 2) & 3, g = t & 3;
    float se = 0.f, sq = 0.f;
    for (int ci = 0; ci < 16; ++ci) {
      int c = g * 16 + ci;
      const float* ch = colh2 + ((size_t)(br * 4 + b) * 64 + c) * 3;
      float Eh = ch[0] * invR, Eh2 = ch[1] * invR, Ezh = ch[2] * invR;
      const float* zs = zst + ((size_t)(b * 2 + br) * 64 + c) * 2;
      float Ez = zs[0] * invR, Ez2 = zs[1] * invR;
      float a = ab[br][b][c][0], bt = ab[br][b][c][1];
      se += Ez + a * Eh + bt;
      sq += Ez2 + a * a * Eh2 + bt * bt + 2.f * a * Ezh + 2.f * bt * Ez + 2.f * a * bt * Eh;
    }
    float m3 = se * 0.0625f;
    float var = sq * 0.0625f - m3 * m3;
    gn3[t * 2] = m3;
    gn3[t * 2 + 1] = rsqrtf(var + 1e-5f);
  }
}

// ---------------- h3 + norm3 fused single pass ----------------
__global__ __launch_bounds__(256)
void k_h3final(const float* __restrict__ h2, const float* __restrict__ z,
               const float* __restrict__ alpha, const float* __restrict__ beta,
               const float* __restrict__ gn3, const float* __restrict__ g3w,
               const float* __restrict__ g3b, int br, float* __restrict__ out) {
  int t = threadIdx.x, bid = blockIdx.x;
  int b = bid >> 6, rc = bid & 63;
  int col = t & 63, rq = t >> 6;
  int g = col >> 4;
  float a = alpha[(br * 4 + b) * 64 + col];
  float bt = beta[(br * 4 + b) * 64 + col];
  float m3 = gn3[((br * 4 + b) * 4 + g) * 2];
  float r3 = gn3[((br * 4 + b) * 4 + g) * 2 + 1];
  float A2 = r3 * g3w[col];
  float B2 = g3b[col] - m3 * A2;
  size_t hbase = (size_t)b * 1048576 + (size_t)rc * 16384;
  size_t zbase = (size_t)(b * 2 + br) * 1048576 + (size_t)rc * 16384;
  for (int j = 0; j < 64; ++j) {
    size_t off = (size_t)(rq + 4 * j) * 64 + col;
    float h3 = z[zbase + off] + a * h2[hbase + off] + bt;
    out[zbase + off] = h3 * A2 + B2;
  }
}

extern "C" void kernel_launch(void* const* d_in, const int* in_sizes, int n_in,
                              void* d_out, int out_size, void* d_ws, size_t ws_size,
                              hipStream_t stream) {
  const float* z   = (const float*)d_in[0];
  const float* x   = (const float*)d_in[1];
  const float* fw1 = (const float*)d_in[2];
  const float* fw2 = (const float*)d_in[3];
  const float* P[20];
  for (int i = 0; i < 20; ++i) P[i] = (const float*)d_in[4 + i];
  // P[0..9] = b_{l1w,l1b,l2w,l2b,g1w,g1b,g2w,g2b,g3w,g3b}; P[10..19] = f_{...}

  float* ws = (float*)d_ws;
  float* xo   = ws + OFF_XO;
  float* S1   = ws + OFF_S1;
  float* XF   = ws + OFF_XF;
  float* G    = ws + OFF_G;
  float* T    = ws + OFF_T;
  float* wt   = ws + OFF_WT;
  float* TW1t = ws + OFF_TW1;
  float* TW2t = ws + OFF_TW2;
  float* CKt  = ws + OFF_CK;
  float* CMt  = ws + OFF_CM;
  float* h2   = ws + OFF_H2;
  float* SS   = ws + OFF_SS;
  float* CS   = ws + OFF_CS;
  float* colq = ws + OFF_COLQ;
  float* colh2= ws + OFF_COLH2;
  float* zst  = ws + OFF_ZST;
  float* cola = ws + OFF_COLA;
  float* gn1  = ws + OFF_GN1;
  float* alph = ws + OFF_ALPHA;
  float* beta = ws + OFF_BETA;
  float* gn3  = ws + OFF_GN3;
  float* out  = (float*)d_out;

  hipMemsetAsync(SS, 0, ZERO_CNT * sizeof(float), stream);
  k_twfill<<<144, 256, 0, stream>>>(TW1t);
  k_wtrans<<<512, 256, 0, stream>>>(fw1, fw2, wt);
  k_fft1<<<512, 256, 0, stream>>>(x, z, TW1t, S1);
  k_fft2<<<128, 256, 0, stream>>>(S1, TW2t, XF);
  k_einsum<<<512, 256, 0, stream>>>(XF, wt, G);
  k_inv1<<<512, 256, 0, stream>>>(G, CKt, T);
  k_inv2<<<1024, 256, 0, stream>>>(T, CMt, xo);
  k_xostats<<<512, 256, 0, stream>>>(xo, SS, CS);
  k_colq<<<64, 256, 0, stream>>>(P[0], P[10], SS, CS, colq, cola);
  k_gstats<<<1, 256, 0, stream>>>(colq, cola, P[1], P[11], gn1);
  k_zstats<<<512, 256, 0, stream>>>(z, zst);
  for (int br = 0; br < 2; ++br) {
    const float* const* q = P + br * 10;
    k_ffn<<<1024, 256, 0, stream>>>(xo, q[0], q[1], q[4], q[5], gn1 + br * 128,
                                    q[2], q[3], z, br, h2 + (size_t)br * 4194304, colh2);
  }
  k_fstats<<<1, 256, 0, stream>>>(colh2, zst, P[6], P[7], P[16], P[17], alph, beta, gn3);
  for (int br = 0; br < 2; ++br) {
    const float* const* q = P + br * 10;
    k_h3final<<<256, 256, 0, stream>>>(h2 + (size_t)br * 4194304, z, alph, beta, gn3,
                                       q[8], q[9], br, out);
  }
}